// Round 10
// baseline (144.633 us; speedup 1.0000x reference)
//
#include <hip/hip_runtime.h>
#include <hip/hip_fp16.h>
#include <math.h>

static constexpr int BATCH = 2048;

// ---------------------------------------------------------------------------
// ws layout:
//   bytes [0, 910336): f16 step-major weight stream, 127 steps x 7168 B.
//     Per step (lane L = 0..63):
//       A  (P2 lo rows t0..3)  at    0 + 32L: u32x8 = [t0 s0s1][t0 s2s3][t1 ..]..[t3 ..]
//       B1 (P1 col lo|hi)      at 2048 + 16L: u32x4 = [s0s1][s2s3][h0h1][h2h3]
//       B2 (P2 hi rows t0..3)  at 3072 + 32L: u32x8
//       B3 (P3 rows t0..3)     at 5120 + 32L: u32x8 = [t0 o0o1][t0 o2o3][t1 ..]..
//   floats [227584, +2048): P2X[4][512]  extra-unit (508+t) rows, slot-ordered
//   floats [229632, +1024): P3X[4][256]
// slot s = 4i+t <-> unit 127t+i (i<127) or 508+t (i=127); deg(unit j)=j%127
// (j<508) else j-508.  Degree-i units: lane i&63, regs {t} (i<64) / {4+t}.
//
// Round 10: R=1 row/wave, 512 blocks -> 2 blocks/CU, 2 waves/SIMD (round-9
// lesson: byte/beat reduction is null; the binder is single-wave dependency
// stalls -> add TLP).  Round-9 address clamp reverted (cost > benefit).
// ---------------------------------------------------------------------------
static constexpr int STEP_BYTES = 7168;
static constexpr int X2_FOFF    = 227584;           // floats
static constexpr int X3_FOFF    = X2_FOFF + 2048;   // floats

__device__ __forceinline__ int sigmaInvU(int s) {
    int i = s >> 2, t = s & 3;
    return (i == 127) ? (508 + t) : (127 * t + i);
}
__device__ __forceinline__ int degU(int x) {
    return (x < 508) ? (x % 127) : (x - 508);
}
__device__ __forceinline__ float fc(float4 v, int k) {
    return k == 0 ? v.x : k == 1 ? v.y : k == 2 ? v.z : v.w;
}
__device__ __forceinline__ unsigned uc(uint4 v, int k) {
    return k == 0 ? v.x : k == 1 ? v.y : k == 2 ? v.z : v.w;
}
__device__ __forceinline__ float hlo(unsigned u) {
    return __half2float(__ushort_as_half((unsigned short)(u & 0xffffu)));
}
__device__ __forceinline__ float hhi(unsigned u) {
    return __half2float(__ushort_as_half((unsigned short)(u >> 16)));
}
// Uniform-lane broadcast via v_readlane (VALU pipe, SGPR result).
__device__ __forceinline__ float rl(float v, int l) {
    return __int_as_float(__builtin_amdgcn_readlane(__float_as_int(v), l));
}

// ---------------------------------------------------------------------------
// Prep: unchanged (passing since round 8).  Each thread produces one 16B
// stream chunk; tail threads fill the f32 extra-unit tables.
// ---------------------------------------------------------------------------
__global__ __launch_bounds__(256) void maf_prep(
    const float* __restrict__ W1, const float* __restrict__ W2,
    const float* __restrict__ W3, float* __restrict__ ws)
{
    const int NCH = 127 * 448;          // 16B chunks in the stream
    int q = blockIdx.x * 256 + threadIdx.x;
    if (q < NCH) {
        int i = q / 448, rem = q % 448;
        unsigned short h[8];
        if (rem < 128) {                // A: P2 lo
            int L = rem >> 1, f = rem & 1;
#pragma unroll
            for (int e = 0; e < 8; ++e) {
                int t = 2 * f + (e >> 2), c = e & 3;
                int cu = 127 * c + L;                    // unit of slot 4L+c
                float v = (L >= i) ? W2[cu * 512 + 127 * t + i] : 0.f;
                h[e] = __half_as_ushort(__float2half(v));
            }
        } else if (rem < 192) {         // B1: P1 col, lo|hi interleaved
            int L = rem - 128;
#pragma unroll
            for (int e = 0; e < 8; ++e) {
                int s = (e < 4) ? (4 * L + e) : (256 + 4 * L + (e - 4));
                int cu = sigmaInvU(s);
                int dg = degU(cu);
                float v = (dg >= i) ? W1[cu * 128 + i] : 0.f;
                h[e] = __half_as_ushort(__float2half(v));
            }
        } else if (rem < 320) {         // B2: P2 hi
            int idx = rem - 192, L = idx >> 1, f = idx & 1;
#pragma unroll
            for (int e = 0; e < 8; ++e) {
                int t = 2 * f + (e >> 2), c = e & 3;
                int cu = sigmaInvU(256 + 4 * L + c);
                int dg = degU(cu);
                float v = (dg >= i) ? W2[cu * 512 + 127 * t + i] : 0.f;
                h[e] = __half_as_ushort(__float2half(v));
            }
        } else {                        // B3: P3
            int idx = rem - 320, L = idx >> 1, f = idx & 1;
#pragma unroll
            for (int e = 0; e < 8; ++e) {
                int t = 2 * f + (e >> 2), c = e & 3;
                int o = 4 * L + c;
                float v = ((o & 127) - 1 >= i) ? W3[o * 512 + 127 * t + i] : 0.f;
                h[e] = __half_as_ushort(__float2half(v));
            }
        }
        uint4 o4;
        o4.x = (unsigned)h[0] | ((unsigned)h[1] << 16);
        o4.y = (unsigned)h[2] | ((unsigned)h[3] << 16);
        o4.z = (unsigned)h[4] | ((unsigned)h[5] << 16);
        o4.w = (unsigned)h[6] | ((unsigned)h[7] << 16);
        *(uint4*)((char*)ws + (size_t)q * 16) = o4;
    } else if (q < NCH + 768) {         // extra-unit f32 tables
        int e = q - NCH;
        if (e < 512) {                  // P2X[t][512]
            int t = e >> 7, s0 = (e & 127) * 4;
            float4 o4;
#pragma unroll
            for (int c = 0; c < 4; ++c) {
                int cu = sigmaInvU(s0 + c);
                float v = (degU(cu) >= t) ? W2[cu * 512 + 508 + t] : 0.f;
                if (c == 0) o4.x = v; else if (c == 1) o4.y = v;
                else if (c == 2) o4.z = v; else o4.w = v;
            }
            *(float4*)(ws + X2_FOFF + t * 512 + s0) = o4;
        } else {                        // P3X[t][256]
            int e2 = e - 512;
            int t = e2 >> 6, o0 = (e2 & 63) * 4;
            float4 o4;
#pragma unroll
            for (int c = 0; c < 4; ++c) {
                int o = o0 + c;
                float v = ((o & 127) - 1 >= t) ? W3[o * 512 + 508 + t] : 0.f;
                if (c == 0) o4.x = v; else if (c == 1) o4.y = v;
                else if (c == 2) o4.z = v; else o4.w = v;
            }
            *(float4*)(ws + X3_FOFF + t * 256 + o0) = o4;
        }
    }
}

// ---------------------------------------------------------------------------
// Double-buffered NAMED uint4 weight registers (7 per set).  Loads are
// unconditional per phase (wave-uniform count, countable vmcnt — round-7
// lesson); offsets precomputed per lane (round-9 lesson: no per-step address
// math).  sched_barrier(0) pins issue order (round-5/6 lesson).
// ---------------------------------------------------------------------------
#define DECL_WSET(P) \
    uint4 P##a0{}, P##a1{}, P##b0{}, P##b1{}, P##b2{}, P##b3{}, P##b4{};

#define LOADS_LO(P) do { \
    P##a0 = *(const uint4*)(sb + offA); \
    P##a1 = *(const uint4*)(sb + offA + 16); \
    P##b0 = *(const uint4*)(sb + offB1); \
    P##b1 = *(const uint4*)(sb + offB2); \
    P##b2 = *(const uint4*)(sb + offB2 + 16); \
    P##b3 = *(const uint4*)(sb + offB3); \
    P##b4 = *(const uint4*)(sb + offB3 + 16); \
    sb += STEP_BYTES; \
    __builtin_amdgcn_sched_barrier(0); \
} while (0)

#define LOADS_HI(P) do { \
    P##b0 = *(const uint4*)(sb + offB1); \
    P##b1 = *(const uint4*)(sb + offB2); \
    P##b2 = *(const uint4*)(sb + offB2 + 16); \
    P##b3 = *(const uint4*)(sb + offB3); \
    P##b4 = *(const uint4*)(sb + offB3 + 16); \
    sb += STEP_BYTES; \
    __builtin_amdgcn_sched_barrier(0); \
} while (0)

#define L2ONE(P, T, LO) do { \
    const float hv = rl(fmaxf(LO ? h1[T] : h1[4 + (T)], 0.f), l0); \
    if (LO) { \
        const unsigned m0 = uc((T) < 2 ? P##a0 : P##a1, 2 * ((T) & 1)); \
        const unsigned m1 = uc((T) < 2 ? P##a0 : P##a1, 2 * ((T) & 1) + 1); \
        h2[0] = fmaf(hlo(m0), hv, h2[0]); h2[1] = fmaf(hhi(m0), hv, h2[1]); \
        h2[2] = fmaf(hlo(m1), hv, h2[2]); h2[3] = fmaf(hhi(m1), hv, h2[3]); \
    } \
    const unsigned n0 = uc((T) < 2 ? P##b1 : P##b2, 2 * ((T) & 1)); \
    const unsigned n1 = uc((T) < 2 ? P##b1 : P##b2, 2 * ((T) & 1) + 1); \
    h2[4] = fmaf(hlo(n0), hv, h2[4]); h2[5] = fmaf(hhi(n0), hv, h2[5]); \
    h2[6] = fmaf(hlo(n1), hv, h2[6]); h2[7] = fmaf(hhi(n1), hv, h2[7]); \
} while (0)

#define L3ONE(P, T, LO) do { \
    const float gv = rl(fmaxf(LO ? h2[T] : h2[4 + (T)], 0.f), l0); \
    const unsigned p0 = uc((T) < 2 ? P##b3 : P##b4, 2 * ((T) & 1)); \
    const unsigned p1 = uc((T) < 2 ? P##b3 : P##b4, 2 * ((T) & 1) + 1); \
    z[0] = fmaf(hlo(p0), gv, z[0]); z[1] = fmaf(hhi(p0), gv, z[1]); \
    z[2] = fmaf(hlo(p1), gv, z[2]); z[3] = fmaf(hhi(p1), gv, z[3]); \
} while (0)

// One inversion step.  I may be runtime; LO must be a literal == ((I) < 64).
#define STEP(I, P, LO) do { \
    const int l0 = (I) & 63, lm = (I) >> 2, rs = (I) & 3; \
    float zs = rs == 0 ? z[0] : rs == 1 ? z[1] : rs == 2 ? z[2] : z[3]; \
    const float mu = rl(zs, lm), sg = rl(zs, 32 + lm); \
    const float ui = rl(LO ? u0 : u1, l0); \
    const float xi = fmaf(ui, __expf(sg), mu); \
    ld += sg; \
    if (lane == l0) { if (LO) x0 = xi; else x1 = xi; } \
    if (LO) { \
        h1[0] = fmaf(hlo(P##b0.x), xi, h1[0]); \
        h1[1] = fmaf(hhi(P##b0.x), xi, h1[1]); \
        h1[2] = fmaf(hlo(P##b0.y), xi, h1[2]); \
        h1[3] = fmaf(hhi(P##b0.y), xi, h1[3]); \
    } \
    h1[4] = fmaf(hlo(P##b0.z), xi, h1[4]); \
    h1[5] = fmaf(hhi(P##b0.z), xi, h1[5]); \
    h1[6] = fmaf(hlo(P##b0.w), xi, h1[6]); \
    h1[7] = fmaf(hhi(P##b0.w), xi, h1[7]); \
    L2ONE(P, 0, LO); L2ONE(P, 1, LO); L2ONE(P, 2, LO); L2ONE(P, 3, LO); \
    if (LO && (I) < 4) { \
        float e1 = (I) == 0 ? h1[4] : (I) == 1 ? h1[5] : (I) == 2 ? h1[6] : h1[7]; \
        const float hv = rl(fmaxf(e1, 0.f), 63); \
        const float4 wl = *(const float4*)(P2X + (I) * 512 + 4 * lane); \
        const float4 wh = *(const float4*)(P2X + (I) * 512 + 256 + 4 * lane); \
        _Pragma("unroll") for (int r = 0; r < 4; ++r) { \
            h2[r] = fmaf(fc(wl, r), hv, h2[r]); \
            h2[4 + r] = fmaf(fc(wh, r), hv, h2[4 + r]); } \
    } \
    L3ONE(P, 0, LO); L3ONE(P, 1, LO); L3ONE(P, 2, LO); L3ONE(P, 3, LO); \
    if (LO && (I) < 4) { \
        float e2 = (I) == 0 ? h2[4] : (I) == 1 ? h2[5] : (I) == 2 ? h2[6] : h2[7]; \
        const float gv = rl(fmaxf(e2, 0.f), 63); \
        const float4 w4 = *(const float4*)(P3X + (I) * 256 + 4 * lane); \
        _Pragma("unroll") for (int s = 0; s < 4; ++s) \
            z[s] = fmaf(fc(w4, s), gv, z[s]); \
    } \
} while (0)

__global__ __launch_bounds__(256, 2) void maf_inverse(
    const float* __restrict__ u, const float* __restrict__ b1,
    const float* __restrict__ b2, const float* __restrict__ b3,
    const float* __restrict__ ws, float* __restrict__ out)
{
    const float* P2X = ws + X2_FOFF;
    const float* P3X = ws + X3_FOFF;

    const int td = threadIdx.x;
    const int lane = td & 63;
    const int wid = td >> 6;
    const int row = blockIdx.x * 4 + wid;     // 512 blocks x 4 waves = 2048 rows

    // state: h slots {4*lane+r} (regs 0..3) / {256+4*lane+r} (regs 4..7);
    // z outputs {4*lane+s}.
    float h1[8], h2[8], z[4];
#pragma unroll
    for (int r = 0; r < 8; ++r) {
        int s = (r < 4) ? (4 * lane + r) : (256 + 4 * lane + (r - 4));
        int uu = sigmaInvU(s);
        h1[r] = b1[uu]; h2[r] = b2[uu];
    }
    {
        const float4 bz = *(const float4*)(b3 + 4 * lane);
        z[0] = bz.x; z[1] = bz.y; z[2] = bz.z; z[3] = bz.w;
    }
    const float u0 = u[row * 128 + lane], u1 = u[row * 128 + 64 + lane];

    float x0 = 0.f, x1 = 0.f, ld = 0.f;

    // stream cursor (uniform) + precomputed per-lane offsets
    const char* sb = (const char*)ws;
    const int offA  = 32 * lane;
    const int offB1 = 2048 + 16 * lane;
    const int offB2 = 3072 + 32 * lane;
    const int offB3 = 5120 + 32 * lane;

    DECL_WSET(wa)
    DECL_WSET(wb)

    LOADS_LO(wa);                    // step 0
#pragma unroll 1
    for (int i = 0; i < 62; i += 2) {        // steps 0..61
        LOADS_LO(wb);
        STEP(i, wa, true);
        LOADS_LO(wa);
        STEP(i + 1, wb, true);
    }
    // bridge: steps 62,63; loads 63 (lo), 64 (hi)
    LOADS_LO(wb);
    STEP(62, wa, true);
    LOADS_HI(wa);
    STEP(63, wb, true);
#pragma unroll 1
    for (int i = 64; i < 126; i += 2) {      // steps 64..125
        LOADS_HI(wb);
        STEP(i, wa, false);
        LOADS_HI(wa);
        STEP(i + 1, wb, false);
    }
    STEP(126, wa, false);

    // step 127: no propagation — x_127 and logdet only (mu=z[127], sg=z[255])
    {
        const float mu = rl(z[3], 31), sg = rl(z[3], 63);
        const float ui = rl(u1, 63);
        const float xi = fmaf(ui, __expf(sg), mu);
        ld += sg;
        if (lane == 63) x1 = xi;
    }

    out[row * 128 + lane]      = x0;
    out[row * 128 + 64 + lane] = x1;
    if (lane == 0) out[BATCH * 128 + row] = ld;
}

extern "C" void kernel_launch(void* const* d_in, const int* in_sizes, int n_in,
                              void* d_out, int out_size, void* d_ws, size_t ws_size,
                              hipStream_t stream)
{
    const float* u  = (const float*)d_in[0];
    const float* W1 = (const float*)d_in[1];
    const float* b1 = (const float*)d_in[2];
    const float* W2 = (const float*)d_in[3];
    const float* b2 = (const float*)d_in[4];
    const float* W3 = (const float*)d_in[5];
    const float* b3 = (const float*)d_in[6];
    // masks computed analytically in maf_prep; d_in[7..9] unused.
    float* ws  = (float*)d_ws;
    float* out = (float*)d_out;
    (void)ws_size; (void)in_sizes; (void)n_in; (void)out_size;

    maf_prep<<<226, 256, 0, stream>>>(W1, W2, W3, ws);
    maf_inverse<<<512, 256, 0, stream>>>(u, b1, b2, b3, ws, out);
}